// Round 1
// baseline (965.181 us; speedup 1.0000x reference)
//
#include <hip/hip_runtime.h>
#include <math.h>

#define BB 16
#define NN 128
#define HH 256
#define EE (NN*(NN-1))   // 16256

typedef unsigned short ushort_t;
typedef __attribute__((ext_vector_type(8))) short bf16x8;
typedef __attribute__((ext_vector_type(4))) float f32x4;

__device__ __forceinline__ ushort_t f2b(float f) {
  // RNE float->bf16 (finite inputs only here)
  unsigned u = __builtin_bit_cast(unsigned, f);
  unsigned r = (u + 0x7fffu + ((u >> 16) & 1u)) >> 16;
  return (ushort_t)r;
}

// ---------------------------------------------------------------------------
// K1: per-node geometry + rel_feat (15)
// geom layout (stride 16): [px,py,vx,vy,theta,c,s,lpx,lpy,lvx,lvy,lfx,lfy]
// ---------------------------------------------------------------------------
__global__ void k_node_geom(const float* __restrict__ inputs,
                            const float* __restrict__ pfield,
                            float* __restrict__ geom, float* __restrict__ relf) {
  int idx = blockIdx.x * blockDim.x + threadIdx.x;
  if (idx >= BB * NN) return;
  float px = inputs[idx*4+0], py = inputs[idx*4+1];
  float vx = inputs[idx*4+2], vy = inputs[idx*4+3];
  float fx = pfield[idx*2+0], fy = pfield[idx*2+1];
  float th = atan2f(vy, vx);
  float c = cosf(th), s = sinf(th);
  float lpx =  c*px + s*py, lpy = -s*px + c*py;
  float lvx =  c*vx + s*vy, lvy = -s*vx + c*vy;
  float lfx =  c*fx + s*fy, lfy = -s*fx + c*fy;
  float np_ = sqrtf(px*px + py*py + 1e-8f);
  float nv_ = sqrtf(vx*vx + vy*vy + 1e-8f);
  float ang  = atan2f(lpy, lpx);
  float vang = atan2f(lvy, lvx);
  float* g = geom + idx*16;
  g[0]=px; g[1]=py; g[2]=vx; g[3]=vy; g[4]=th; g[5]=c; g[6]=s;
  g[7]=lpx; g[8]=lpy; g[9]=lvx; g[10]=lvy; g[11]=lfx; g[12]=lfy;
  float* r = relf + idx*16;
  r[0]=lpx; r[1]=lpy; r[2]=lvx; r[3]=lvy; r[4]=np_; r[5]=ang; r[6]=nv_; r[7]=vang; r[8]=th;
  r[9]=lpx; r[10]=lpy; r[11]=lvx; r[12]=lvy; r[13]=lfx; r[14]=lfy;
}

// ---------------------------------------------------------------------------
// Kcvt: msg_fc2_w[1], pm_fc2_w[1] -> bf16
// ---------------------------------------------------------------------------
__global__ void k_cvt(const float* __restrict__ w2, const float* __restrict__ pw2,
                      ushort_t* __restrict__ w2b, ushort_t* __restrict__ pw2b) {
  int idx = blockIdx.x * 256 + threadIdx.x;   // 0..131071
  if (idx < HH*HH) w2b[idx] = f2b(w2[HH*HH + idx]);
  else { int k = idx - HH*HH; pw2b[k] = f2b(pw2[HH*HH + k]); }
}

// ---------------------------------------------------------------------------
// K2: Ha = hidden@W1a.T + b1, Hb = hidden@W1b.T   (W1 = msg_fc1_w[1])
// grid 256: block = (node n, batch-half), 8 rows each
// ---------------------------------------------------------------------------
__global__ __launch_bounds__(256) void k_hab(const float* __restrict__ hidden,
                                             const float* __restrict__ w1,
                                             const float* __restrict__ b1,
                                             float* __restrict__ Ha,
                                             float* __restrict__ Hb) {
  int n = blockIdx.x >> 1, half = blockIdx.x & 1;
  int tid = threadIdx.x;
  __shared__ float x[8][HH];
  for (int q = 0; q < 8; ++q) {
    int b = half*8 + q;
    x[q][tid] = hidden[(b*NN + n)*HH + tid];
  }
  __syncthreads();
  const float* wa = w1 + (HH*2*HH) + tid*(2*HH);  // slice i=1, row tid
  const float* wb = wa + HH;
  float accA[8], accB[8];
  float bias = b1[HH + tid];
  #pragma unroll
  for (int q = 0; q < 8; ++q) { accA[q] = bias; accB[q] = 0.f; }
  for (int k = 0; k < HH; k += 4) {
    float4 a4 = *(const float4*)(wa + k);
    float4 b4 = *(const float4*)(wb + k);
    #pragma unroll
    for (int q = 0; q < 8; ++q) {
      float4 x4 = *(const float4*)(&x[q][k]);
      accA[q] += x4.x*a4.x + x4.y*a4.y + x4.z*a4.z + x4.w*a4.w;
      accB[q] += x4.x*b4.x + x4.y*b4.y + x4.z*b4.z + x4.w*b4.w;
    }
  }
  for (int q = 0; q < 8; ++q) {
    int b = half*8 + q;
    Ha[(b*NN + n)*HH + tid] = accA[q];
    Hb[(b*NN + n)*HH + tid] = accB[q];
  }
}

// ---------------------------------------------------------------------------
// K3: per (b, recv j): both edge MLPs, fused fc2 GEMM (bf16 MFMA) + weighted
// column-sum aggregation. Row i of the 128-row tile = sender i (i==j: wgt 0).
// LDS m1s is bf16 [128][256], XOR-swizzled: byte ^= (row&7)<<4.
// ---------------------------------------------------------------------------
__global__ __launch_bounds__(256) void k_edge(
    const float* __restrict__ Ha, const float* __restrict__ Hb,
    const float* __restrict__ geom, const float* __restrict__ edges,
    const ushort_t* __restrict__ w2b, const float* __restrict__ b2,
    const ushort_t* __restrict__ pw2b, const float* __restrict__ pb2,
    const float* __restrict__ pw1, const float* __restrict__ pb1,
    float* __restrict__ agg, float* __restrict__ pagg) {
  int b = blockIdx.x >> 7, j = blockIdx.x & 127;
  int tid = threadIdx.x;
  int lane = tid & 63;
  int wv = tid >> 6;            // wave 0..3 -> cols wv*64..wv*64+63
  int lrow = lane & 15, lk = lane >> 4;

  __shared__ __align__(16) unsigned char m1s[128*512];  // 64 KB bf16 [128][256]
  __shared__ float attrS[128][24];
  __shared__ float HajS[HH];
  __shared__ float wgtS[128];
  __shared__ float gjS[13];

  HajS[tid] = Ha[(b*NN + j)*HH + tid];
  if (tid < 13) gjS[tid] = geom[(b*NN + j)*16 + tid];
  __syncthreads();

  // ---- phase A: edge attrs + weights (threads 0..127, one sender each) ----
  if (tid < 128) {
    int i = tid;
    const float* gi = geom + (b*NN + i)*16;
    float dpx = gi[0]-gjS[0], dpy = gi[1]-gjS[1];
    float dvx = gi[2]-gjS[2], dvy = gi[3]-gjS[3];
    float dth = gi[4]-gjS[4];
    float cj = gjS[5], sj = gjS[6];
    float ci = gi[5],  si = gi[6];
    float ndp = sqrtf(dpx*dpx + dpy*dpy + 1e-8f);
    float ndv = sqrtf(dvx*dvx + dvy*dvy + 1e-8f);
    // f1: R_recv applied to (dp, dv), dth
    float r1x =  cj*dpx + sj*dpy, r1y = -sj*dpx + cj*dpy;
    float v1x =  cj*dvx + sj*dvy, v1y = -sj*dvx + cj*dvy;
    attrS[i][0]=r1x; attrS[i][1]=r1y; attrS[i][2]=v1x; attrS[i][3]=v1y;
    attrS[i][4]=ndp; attrS[i][5]=atan2f(r1y, r1x);
    attrS[i][6]=ndv; attrS[i][7]=atan2f(v1y, v1x); attrS[i][8]=dth;
    // f2: R_send applied to (-dp, -dv), -dth
    float r2x = -(ci*dpx + si*dpy), r2y = si*dpx - ci*dpy;
    float v2x = -(ci*dvx + si*dvy), v2y = si*dvx - ci*dvy;
    attrS[i][9]=r2x; attrS[i][10]=r2y; attrS[i][11]=v2x; attrS[i][12]=v2y;
    attrS[i][13]=ndp; attrS[i][14]=atan2f(r2y, r2x);
    attrS[i][15]=ndv; attrS[i][16]=atan2f(v2y, v2x); attrS[i][17]=-dth;
    attrS[i][18]=gjS[7]; attrS[i][19]=gjS[8]; attrS[i][20]=gjS[9];
    attrS[i][21]=gjS[10]; attrS[i][22]=gjS[11]; attrS[i][23]=gjS[12];
    float w = 0.f;
    if (i != j) {
      int e = i*127 + (j < i ? j : j-1);
      w = edges[(b*EE + e)*2 + 1];
    }
    wgtS[i] = w;
  }

  // ---- phase B1: m1[i][h] = tanh(Ha[j][h] + Hb[i][h]) -> bf16 LDS ----
  {
    float haj = HajS[tid];
    const float* hb = Hb + b*NN*HH + tid;
    #pragma unroll 2
    for (int i = 0; i < 128; ++i) {
      float v = tanhf(haj + hb[i*HH]);
      *(ushort_t*)(m1s + i*512 + ((tid*2) ^ ((i&7)<<4))) = f2b(v);
    }
  }
  __syncthreads();

  f32x4 zero = {0.f, 0.f, 0.f, 0.f};

  // ---- GEMM1: m2 = tanh(m1 @ W2.T + b2); agg[j] = sum_i m2[i]*wgt[i] /127 --
  {
    f32x4 acc[8][4];
    #pragma unroll
    for (int rt = 0; rt < 8; ++rt)
      #pragma unroll
      for (int nt = 0; nt < 4; ++nt) acc[rt][nt] = zero;
    for (int kk = 0; kk < 8; ++kk) {
      bf16x8 afr[8];
      #pragma unroll
      for (int rt = 0; rt < 8; ++rt) {
        int row = rt*16 + lrow;
        afr[rt] = *reinterpret_cast<const bf16x8*>(
            m1s + row*512 + ((kk*64 + lk*16) ^ ((row&7)<<4)));
      }
      #pragma unroll
      for (int nt = 0; nt < 4; ++nt) {
        int col = wv*64 + nt*16 + lrow;
        bf16x8 bfr = *reinterpret_cast<const bf16x8*>(w2b + col*HH + kk*32 + lk*8);
        #pragma unroll
        for (int rt = 0; rt < 8; ++rt)
          acc[rt][nt] = __builtin_amdgcn_mfma_f32_16x16x32_bf16(afr[rt], bfr, acc[rt][nt], 0, 0, 0);
      }
    }
    #pragma unroll
    for (int nt = 0; nt < 4; ++nt) {
      int col = wv*64 + nt*16 + lrow;
      float bias = b2[col];
      float p = 0.f;
      #pragma unroll
      for (int rt = 0; rt < 8; ++rt)
        #pragma unroll
        for (int r = 0; r < 4; ++r) {
          int row = rt*16 + lk*4 + r;
          p += tanhf(acc[rt][nt][r] + bias) * wgtS[row];
        }
      p += __shfl_xor(p, 16);
      p += __shfl_xor(p, 32);
      if (lane < 16)
        agg[(b*NN + j)*HH + wv*64 + nt*16 + lane] = p * (1.0f/127.0f);
    }
  }
  __syncthreads();

  // ---- phase B2: p1[i][h] = relu(attr[i] . pw1[h] + pb1[h]) -> bf16 LDS ----
  {
    float wrow[24];
    #pragma unroll
    for (int k = 0; k < 24; ++k) wrow[k] = pw1[tid*24 + k];
    float bias = pb1[tid];
    for (int i = 0; i < 128; ++i) {
      float s = bias;
      #pragma unroll
      for (int k = 0; k < 24; k += 4) {
        float4 a4 = *(const float4*)(&attrS[i][k]);
        s += a4.x*wrow[k] + a4.y*wrow[k+1] + a4.z*wrow[k+2] + a4.w*wrow[k+3];
      }
      s = fmaxf(s, 0.f);
      *(ushort_t*)(m1s + i*512 + ((tid*2) ^ ((i&7)<<4))) = f2b(s);
    }
  }
  __syncthreads();

  // ---- GEMM2: p2 = relu(p1 @ pW2.T + pb2); pagg likewise ----
  {
    f32x4 acc[8][4];
    #pragma unroll
    for (int rt = 0; rt < 8; ++rt)
      #pragma unroll
      for (int nt = 0; nt < 4; ++nt) acc[rt][nt] = zero;
    for (int kk = 0; kk < 8; ++kk) {
      bf16x8 afr[8];
      #pragma unroll
      for (int rt = 0; rt < 8; ++rt) {
        int row = rt*16 + lrow;
        afr[rt] = *reinterpret_cast<const bf16x8*>(
            m1s + row*512 + ((kk*64 + lk*16) ^ ((row&7)<<4)));
      }
      #pragma unroll
      for (int nt = 0; nt < 4; ++nt) {
        int col = wv*64 + nt*16 + lrow;
        bf16x8 bfr = *reinterpret_cast<const bf16x8*>(pw2b + col*HH + kk*32 + lk*8);
        #pragma unroll
        for (int rt = 0; rt < 8; ++rt)
          acc[rt][nt] = __builtin_amdgcn_mfma_f32_16x16x32_bf16(afr[rt], bfr, acc[rt][nt], 0, 0, 0);
      }
    }
    #pragma unroll
    for (int nt = 0; nt < 4; ++nt) {
      int col = wv*64 + nt*16 + lrow;
      float bias = pb2[col];
      float p = 0.f;
      #pragma unroll
      for (int rt = 0; rt < 8; ++rt)
        #pragma unroll
        for (int r = 0; r < 4; ++r) {
          int row = rt*16 + lk*4 + r;
          p += fmaxf(acc[rt][nt][r] + bias, 0.f) * wgtS[row];
        }
      p += __shfl_xor(p, 16);
      p += __shfl_xor(p, 32);
      if (lane < 16)
        pagg[(b*NN + j)*HH + wv*64 + nt*16 + lane] = p * (1.0f/127.0f);
    }
  }
}

// ---------------------------------------------------------------------------
// K4: GRU gates + output MLP + global-frame outputs.
// grid 256: block = (node n, batch-half), 8 rows; thread = output channel h.
// ---------------------------------------------------------------------------
__global__ __launch_bounds__(256) void k_gru(
    const float* __restrict__ inputs, const float* __restrict__ hidden,
    const float* __restrict__ geom, const float* __restrict__ relf,
    const float* __restrict__ agg, const float* __restrict__ pagg,
    const float* __restrict__ hr_w, const float* __restrict__ hi_w, const float* __restrict__ hh_w,
    const float* __restrict__ pr_w, const float* __restrict__ pr_b,
    const float* __restrict__ pi_w, const float* __restrict__ pi_b,
    const float* __restrict__ pn_w, const float* __restrict__ pn_b,
    const float* __restrict__ ir_w, const float* __restrict__ ir_b,
    const float* __restrict__ ii_w, const float* __restrict__ ii_b,
    const float* __restrict__ in_w, const float* __restrict__ in_b,
    const float* __restrict__ ow1, const float* __restrict__ ob1,
    const float* __restrict__ ow2, const float* __restrict__ ob2,
    const float* __restrict__ ow3, const float* __restrict__ ob3,
    float* __restrict__ out_o, float* __restrict__ out_h) {
  int n = blockIdx.x >> 1, half = blockIdx.x & 1;
  int tid = threadIdx.x;
  __shared__ float paS[8][HH], agS[8][HH], hS[8][HH], t0S[8][HH], t1S[8][HH];
  __shared__ float relS[8][16];
  __shared__ float predS[8][4];

  for (int q = 0; q < 8; ++q) {
    int b = half*8 + q;
    int base = (b*NN + n)*HH;
    paS[q][tid] = pagg[base + tid];
    agS[q][tid] = agg[base + tid];
    hS[q][tid]  = hidden[base + tid];
  }
  if (tid < 128) {
    int q = tid >> 4, k = tid & 15;
    int b = half*8 + q;
    relS[q][k] = (k < 15) ? relf[(b*NN + n)*16 + k] : 0.f;
  }
  __syncthreads();

  int h = tid;
  float aR[8], aI[8], aN[8], aH[8];
  float br = ir_b[h] + pr_b[h];
  float bi = ii_b[h] + pi_b[h];
  float bn = in_b[h] + pn_b[h];
  #pragma unroll
  for (int q = 0; q < 8; ++q) { aR[q]=br; aI[q]=bi; aN[q]=bn; aH[q]=0.f; }

  for (int k = 0; k < 15; ++k) {
    float wr = ir_w[h*15+k], wi = ii_w[h*15+k], wn = in_w[h*15+k];
    #pragma unroll
    for (int q = 0; q < 8; ++q) {
      float x = relS[q][k];
      aR[q] += x*wr; aI[q] += x*wi; aN[q] += x*wn;
    }
  }
  for (int k = 0; k < HH; k += 4) {
    float4 wpr = *(const float4*)(pr_w + h*HH + k);
    float4 wpi = *(const float4*)(pi_w + h*HH + k);
    float4 wpn = *(const float4*)(pn_w + h*HH + k);
    float4 whr = *(const float4*)(hr_w + h*HH + k);
    float4 whi = *(const float4*)(hi_w + h*HH + k);
    float4 whh = *(const float4*)(hh_w + h*HH + k);
    #pragma unroll
    for (int q = 0; q < 8; ++q) {
      float4 xp = *(const float4*)(&paS[q][k]);
      float4 xa = *(const float4*)(&agS[q][k]);
      aR[q] += xp.x*wpr.x + xp.y*wpr.y + xp.z*wpr.z + xp.w*wpr.w
             + xa.x*whr.x + xa.y*whr.y + xa.z*whr.z + xa.w*whr.w;
      aI[q] += xp.x*wpi.x + xp.y*wpi.y + xp.z*wpi.z + xp.w*wpi.w
             + xa.x*whi.x + xa.y*whi.y + xa.z*whi.z + xa.w*whi.w;
      aN[q] += xp.x*wpn.x + xp.y*wpn.y + xp.z*wpn.z + xp.w*wpn.w;
      aH[q] += xa.x*whh.x + xa.y*whh.y + xa.z*whh.z + xa.w*whh.w;
    }
  }
  #pragma unroll
  for (int q = 0; q < 8; ++q) {
    int b = half*8 + q;
    float r  = 1.f/(1.f + expf(-aR[q]));
    float ig = 1.f/(1.f + expf(-aI[q]));
    float ng = tanhf(aN[q] + r*aH[q]);
    float hn = (1.f - ig)*ng + ig*hS[q][h];
    out_h[(b*NN + n)*HH + h] = hn;
    t0S[q][h] = hn;
  }
  __syncthreads();

  { // h1 = relu(hn @ ow1.T + ob1)
    float a1[8];
    float bias = ob1[h];
    #pragma unroll
    for (int q = 0; q < 8; ++q) a1[q] = bias;
    for (int k = 0; k < HH; k += 4) {
      float4 w = *(const float4*)(ow1 + h*HH + k);
      #pragma unroll
      for (int q = 0; q < 8; ++q) {
        float4 x = *(const float4*)(&t0S[q][k]);
        a1[q] += x.x*w.x + x.y*w.y + x.z*w.z + x.w*w.w;
      }
    }
    __syncthreads();
    #pragma unroll
    for (int q = 0; q < 8; ++q) t1S[q][h] = fmaxf(a1[q], 0.f);
  }
  __syncthreads();

  { // h2 = relu(h1 @ ow2.T + ob2) -> t0S
    float a2[8];
    float bias = ob2[h];
    #pragma unroll
    for (int q = 0; q < 8; ++q) a2[q] = bias;
    for (int k = 0; k < HH; k += 4) {
      float4 w = *(const float4*)(ow2 + h*HH + k);
      #pragma unroll
      for (int q = 0; q < 8; ++q) {
        float4 x = *(const float4*)(&t1S[q][k]);
        a2[q] += x.x*w.x + x.y*w.y + x.z*w.z + x.w*w.w;
      }
    }
    __syncthreads();
    #pragma unroll
    for (int q = 0; q < 8; ++q) t0S[q][h] = fmaxf(a2[q], 0.f);
  }
  __syncthreads();

  if (tid < 32) {  // pred = h2 @ ow3.T + ob3  (4 outputs)
    int o = tid >> 3, q = tid & 7;
    float acc = ob3[o];
    for (int k = 0; k < HH; ++k) acc += t0S[q][k]*ow3[o*HH + k];
    predS[q][o] = acc;
  }
  __syncthreads();
  if (tid < 8) {
    int q = tid;
    int b = half*8 + q;
    const float* g = geom + (b*NN + n)*16;
    float c = g[5], s = g[6];
    float p0 = predS[q][0], p1 = predS[q][1], p2 = predS[q][2], p3 = predS[q][3];
    int base = (b*NN + n)*4;
    // Rinv = R^T: Rinv.v = (c*vx - s*vy, s*vx + c*vy)
    out_o[base+0] = inputs[base+0] + (c*p0 - s*p1);
    out_o[base+1] = inputs[base+1] + (s*p0 + c*p1);
    out_o[base+2] = inputs[base+2] + (c*p2 - s*p3);
    out_o[base+3] = inputs[base+3] + (s*p2 + c*p3);
  }
}

// ---------------------------------------------------------------------------
extern "C" void kernel_launch(void* const* d_in, const int* in_sizes, int n_in,
                              void* d_out, int out_size, void* d_ws, size_t ws_size,
                              hipStream_t stream) {
  const float* inputs    = (const float*)d_in[0];
  const float* hidden    = (const float*)d_in[1];
  const float* edges     = (const float*)d_in[2];
  const float* pfield    = (const float*)d_in[3];
  const float* msg_fc1_w = (const float*)d_in[4];
  const float* msg_fc1_b = (const float*)d_in[5];
  const float* msg_fc2_w = (const float*)d_in[6];
  const float* msg_fc2_b = (const float*)d_in[7];
  const float* pm_fc1_w  = (const float*)d_in[8];
  const float* pm_fc1_b  = (const float*)d_in[9];
  const float* pm_fc2_w  = (const float*)d_in[10];
  const float* pm_fc2_b  = (const float*)d_in[11];
  const float* hr_w = (const float*)d_in[12];
  const float* hi_w = (const float*)d_in[13];
  const float* hh_w = (const float*)d_in[14];
  const float* pr_w = (const float*)d_in[15];
  const float* pr_b = (const float*)d_in[16];
  const float* pi_w = (const float*)d_in[17];
  const float* pi_b = (const float*)d_in[18];
  const float* pn_w = (const float*)d_in[19];
  const float* pn_b = (const float*)d_in[20];
  const float* ir_w = (const float*)d_in[21];
  const float* ir_b = (const float*)d_in[22];
  const float* ii_w = (const float*)d_in[23];
  const float* ii_b = (const float*)d_in[24];
  const float* in_w = (const float*)d_in[25];
  const float* in_b = (const float*)d_in[26];
  const float* ow1  = (const float*)d_in[27];
  const float* ob1  = (const float*)d_in[28];
  const float* ow2  = (const float*)d_in[29];
  const float* ob2  = (const float*)d_in[30];
  const float* ow3  = (const float*)d_in[31];
  const float* ob3  = (const float*)d_in[32];

  float* ws   = (float*)d_ws;
  float* geom = ws;                 // 32768 f32 (stride-16 × 2048 nodes)
  float* relf = geom + 32768;       // 32768
  float* Ha   = relf + 32768;       // 524288
  float* Hb   = Ha   + 524288;      // 524288
  float* agg  = Hb   + 524288;      // 524288
  float* pagg = agg  + 524288;      // 524288
  ushort_t* w2b  = (ushort_t*)(pagg + 524288);  // 65536 bf16
  ushort_t* pw2b = w2b + HH*HH;                 // 65536 bf16

  float* out_o = (float*)d_out;           // (B,N,4)
  float* out_h = out_o + BB*NN*4;         // (B,N,H)

  k_node_geom<<<dim3(8), dim3(256), 0, stream>>>(inputs, pfield, geom, relf);
  k_cvt<<<dim3(512), dim3(256), 0, stream>>>(msg_fc2_w, pm_fc2_w, w2b, pw2b);
  k_hab<<<dim3(256), dim3(256), 0, stream>>>(hidden, msg_fc1_w, msg_fc1_b, Ha, Hb);
  k_edge<<<dim3(BB*NN), dim3(256), 0, stream>>>(Ha, Hb, geom, edges,
      w2b, msg_fc2_b + HH, pw2b, pm_fc2_b + HH,
      pm_fc1_w + HH*24, pm_fc1_b + HH, agg, pagg);
  k_gru<<<dim3(256), dim3(256), 0, stream>>>(inputs, hidden, geom, relf, agg, pagg,
      hr_w, hi_w, hh_w, pr_w, pr_b, pi_w, pi_b, pn_w, pn_b,
      ir_w, ir_b, ii_w, ii_b, in_w, in_b,
      ow1, ob1, ow2, ob2, ow3, ob3, out_o, out_h);
}

// Round 4
// 483.637 us; speedup vs baseline: 1.9957x; 1.9957x over previous
//
#include <hip/hip_runtime.h>
#include <math.h>

#define BB 16
#define NN 128
#define HH 256
#define EE (NN*(NN-1))   // 16256

typedef unsigned short ushort_t;
typedef __attribute__((ext_vector_type(8))) short bf16x8;
typedef __attribute__((ext_vector_type(4))) float f32x4;

__device__ __forceinline__ ushort_t f2b(float f) {
  unsigned u = __builtin_bit_cast(unsigned, f);
  unsigned r = (u + 0x7fffu + ((u >> 16) & 1u)) >> 16;
  return (ushort_t)r;
}

// fast tanh: (e-1)/(e+1), e = 2^(2x*log2e); clamped, ~6 VALU ops
__device__ __forceinline__ float fast_tanh(float x) {
  float xx = fminf(fmaxf(x, -15.f), 15.f);
  float e = __builtin_amdgcn_exp2f(xx * 2.8853900817779268f);
  return (e - 1.f) * __builtin_amdgcn_rcpf(e + 1.f);
}
__device__ __forceinline__ float fast_sigmoid(float x) {
  float xx = fminf(fmaxf(x, -30.f), 30.f);
  float e = __builtin_amdgcn_exp2f(-xx * 1.4426950408889634f);
  return __builtin_amdgcn_rcpf(1.f + e);
}

// ---------------------------------------------------------------------------
// K1: per-node geometry + rel_feat (15)
// ---------------------------------------------------------------------------
__global__ void k_node_geom(const float* __restrict__ inputs,
                            const float* __restrict__ pfield,
                            float* __restrict__ geom, float* __restrict__ relf) {
  int idx = blockIdx.x * blockDim.x + threadIdx.x;
  if (idx >= BB * NN) return;
  float px = inputs[idx*4+0], py = inputs[idx*4+1];
  float vx = inputs[idx*4+2], vy = inputs[idx*4+3];
  float fx = pfield[idx*2+0], fy = pfield[idx*2+1];
  float th = atan2f(vy, vx);
  float c = cosf(th), s = sinf(th);
  float lpx =  c*px + s*py, lpy = -s*px + c*py;
  float lvx =  c*vx + s*vy, lvy = -s*vx + c*vy;
  float lfx =  c*fx + s*fy, lfy = -s*fx + c*fy;
  float np_ = sqrtf(px*px + py*py + 1e-8f);
  float nv_ = sqrtf(vx*vx + vy*vy + 1e-8f);
  float ang  = atan2f(lpy, lpx);
  float vang = atan2f(lvy, lvx);
  float* g = geom + idx*16;
  g[0]=px; g[1]=py; g[2]=vx; g[3]=vy; g[4]=th; g[5]=c; g[6]=s;
  g[7]=lpx; g[8]=lpy; g[9]=lvx; g[10]=lvy; g[11]=lfx; g[12]=lfy;
  float* r = relf + idx*16;
  r[0]=lpx; r[1]=lpy; r[2]=lvx; r[3]=lvy; r[4]=np_; r[5]=ang; r[6]=nv_; r[7]=vang; r[8]=th;
  r[9]=lpx; r[10]=lpy; r[11]=lvx; r[12]=lvy; r[13]=lfx; r[14]=lfy;
}

// ---------------------------------------------------------------------------
// Kcvt: msg_fc2_w[1], pm_fc2_w[1] -> bf16
// ---------------------------------------------------------------------------
__global__ void k_cvt(const float* __restrict__ w2, const float* __restrict__ pw2,
                      ushort_t* __restrict__ w2b, ushort_t* __restrict__ pw2b) {
  int idx = blockIdx.x * 256 + threadIdx.x;
  if (idx < HH*HH) w2b[idx] = f2b(w2[HH*HH + idx]);
  else { int k = idx - HH*HH; pw2b[k] = f2b(pw2[HH*HH + k]); }
}

// ---------------------------------------------------------------------------
// K2: Ha = hidden@W1a.T + b1, Hb = hidden@W1b.T
// ---------------------------------------------------------------------------
__global__ __launch_bounds__(256) void k_hab(const float* __restrict__ hidden,
                                             const float* __restrict__ w1,
                                             const float* __restrict__ b1,
                                             float* __restrict__ Ha,
                                             float* __restrict__ Hb) {
  int n = blockIdx.x >> 1, half = blockIdx.x & 1;
  int tid = threadIdx.x;
  __shared__ float x[8][HH];
  for (int q = 0; q < 8; ++q) {
    int b = half*8 + q;
    x[q][tid] = hidden[(b*NN + n)*HH + tid];
  }
  __syncthreads();
  const float* wa = w1 + (HH*2*HH) + tid*(2*HH);
  const float* wb = wa + HH;
  float accA[8], accB[8];
  float bias = b1[HH + tid];
  #pragma unroll
  for (int q = 0; q < 8; ++q) { accA[q] = bias; accB[q] = 0.f; }
  for (int k = 0; k < HH; k += 4) {
    float4 a4 = *(const float4*)(wa + k);
    float4 b4 = *(const float4*)(wb + k);
    #pragma unroll
    for (int q = 0; q < 8; ++q) {
      float4 x4 = *(const float4*)(&x[q][k]);
      accA[q] += x4.x*a4.x + x4.y*a4.y + x4.z*a4.z + x4.w*a4.w;
      accB[q] += x4.x*b4.x + x4.y*b4.y + x4.z*b4.z + x4.w*b4.w;
    }
  }
  for (int q = 0; q < 8; ++q) {
    int b = half*8 + q;
    Ha[(b*NN + n)*HH + tid] = accA[q];
    Hb[(b*NN + n)*HH + tid] = accB[q];
  }
}

// ---------------------------------------------------------------------------
// K3: per (b, recv j, half): 64 senders per block.
// m1s bf16 [64][256], XOR-swizzle byte ^= (row&15)<<4.
// grid = B*N*2 = 4096, 4 waves, target 4 blocks/CU.
// ---------------------------------------------------------------------------
__global__ __launch_bounds__(256, 4) void k_edge(
    const float* __restrict__ Ha, const float* __restrict__ Hb,
    const float* __restrict__ geom, const float* __restrict__ edges,
    const ushort_t* __restrict__ w2b, const float* __restrict__ b2,
    const ushort_t* __restrict__ pw2b, const float* __restrict__ pb2,
    const float* __restrict__ pw1, const float* __restrict__ pb1,
    float* __restrict__ agg0, float* __restrict__ agg1,
    float* __restrict__ pagg0, float* __restrict__ pagg1) {
  int half = blockIdx.x & 1;
  int j = (blockIdx.x >> 1) & 127;
  int b = blockIdx.x >> 8;
  int tid = threadIdx.x;
  int lane = tid & 63;
  int wv = tid >> 6;
  int lrow = lane & 15, lk = lane >> 4;

  __shared__ __align__(16) unsigned char m1s[64*512];   // 32 KB bf16 [64][256]
  __shared__ float attrS[64][24];
  __shared__ float HajS[HH];
  __shared__ float wgtS[64];
  __shared__ float gjS[13];

  HajS[tid] = Ha[(b*NN + j)*HH + tid];
  if (tid < 13) gjS[tid] = geom[(b*NN + j)*16 + tid];
  __syncthreads();

  // ---- phase A: edge attrs + weights (threads 0..63, one sender each) ----
  if (tid < 64) {
    int il = tid;
    int i = half*64 + il;
    const float* gi = geom + (b*NN + i)*16;
    float dpx = gi[0]-gjS[0], dpy = gi[1]-gjS[1];
    float dvx = gi[2]-gjS[2], dvy = gi[3]-gjS[3];
    float dth = gi[4]-gjS[4];
    float cj = gjS[5], sj = gjS[6];
    float ci = gi[5],  si = gi[6];
    float ndp = sqrtf(dpx*dpx + dpy*dpy + 1e-8f);
    float ndv = sqrtf(dvx*dvx + dvy*dvy + 1e-8f);
    float r1x =  cj*dpx + sj*dpy, r1y = -sj*dpx + cj*dpy;
    float v1x =  cj*dvx + sj*dvy, v1y = -sj*dvx + cj*dvy;
    attrS[il][0]=r1x; attrS[il][1]=r1y; attrS[il][2]=v1x; attrS[il][3]=v1y;
    attrS[il][4]=ndp; attrS[il][5]=atan2f(r1y, r1x);
    attrS[il][6]=ndv; attrS[il][7]=atan2f(v1y, v1x); attrS[il][8]=dth;
    float r2x = -(ci*dpx + si*dpy), r2y = si*dpx - ci*dpy;
    float v2x = -(ci*dvx + si*dvy), v2y = si*dvx - ci*dvy;
    attrS[il][9]=r2x; attrS[il][10]=r2y; attrS[il][11]=v2x; attrS[il][12]=v2y;
    attrS[il][13]=ndp; attrS[il][14]=atan2f(r2y, r2x);
    attrS[il][15]=ndv; attrS[il][16]=atan2f(v2y, v2x); attrS[il][17]=-dth;
    attrS[il][18]=gjS[7]; attrS[il][19]=gjS[8]; attrS[il][20]=gjS[9];
    attrS[il][21]=gjS[10]; attrS[il][22]=gjS[11]; attrS[il][23]=gjS[12];
    float w = 0.f;
    if (i != j) {
      int e = i*127 + (j < i ? j : j-1);
      w = edges[(b*EE + e)*2 + 1];
    }
    wgtS[il] = w;
  }

  // ---- phase B1: m1[row][h] = tanh(Ha[j][h] + Hb[i][h]) -> bf16 LDS ----
  {
    float haj = HajS[tid];
    const float* hb = Hb + (b*NN + half*64)*HH + tid;
    #pragma unroll
    for (int i0 = 0; i0 < 64; i0 += 8) {
      float v[8];
      #pragma unroll
      for (int u = 0; u < 8; ++u) v[u] = hb[(i0+u)*HH];
      #pragma unroll
      for (int u = 0; u < 8; ++u) {
        int row = i0 + u;
        *(ushort_t*)(m1s + row*512 + ((tid*2) ^ ((row&15)<<4))) =
            f2b(fast_tanh(haj + v[u]));
      }
    }
  }
  __syncthreads();

  f32x4 zero = {0.f, 0.f, 0.f, 0.f};

  // ---- GEMM1: m2 = tanh(m1 @ W2.T + b2); weighted col-sum -> agg partial ---
  {
    f32x4 acc[4][4];
    #pragma unroll
    for (int rt = 0; rt < 4; ++rt)
      #pragma unroll
      for (int nt = 0; nt < 4; ++nt) acc[rt][nt] = zero;
    for (int kk = 0; kk < 8; ++kk) {
      bf16x8 afr[4];
      #pragma unroll
      for (int rt = 0; rt < 4; ++rt) {
        int row = rt*16 + lrow;
        afr[rt] = *reinterpret_cast<const bf16x8*>(
            m1s + row*512 + ((kk*64 + lk*16) ^ ((row&15)<<4)));
      }
      #pragma unroll
      for (int nt = 0; nt < 4; ++nt) {
        int col = wv*64 + nt*16 + lrow;
        bf16x8 bfr = *reinterpret_cast<const bf16x8*>(w2b + col*HH + kk*32 + lk*8);
        #pragma unroll
        for (int rt = 0; rt < 4; ++rt)
          acc[rt][nt] = __builtin_amdgcn_mfma_f32_16x16x32_bf16(afr[rt], bfr, acc[rt][nt], 0, 0, 0);
      }
    }
    float* aggOut = half ? agg1 : agg0;
    #pragma unroll
    for (int nt = 0; nt < 4; ++nt) {
      int col = wv*64 + nt*16 + lrow;
      float bias = b2[col];
      float p = 0.f;
      #pragma unroll
      for (int rt = 0; rt < 4; ++rt)
        #pragma unroll
        for (int r = 0; r < 4; ++r) {
          int row = rt*16 + lk*4 + r;
          p += fast_tanh(acc[rt][nt][r] + bias) * wgtS[row];
        }
      p += __shfl_xor(p, 16);
      p += __shfl_xor(p, 32);
      if (lane < 16)
        aggOut[(b*NN + j)*HH + wv*64 + nt*16 + lane] = p * (1.0f/127.0f);
    }
  }
  __syncthreads();

  // ---- phase B2: p1[row][h] = relu(attr[row] . pw1[h] + pb1[h]) ----
  {
    float wrow[24];
    #pragma unroll
    for (int k = 0; k < 24; ++k) wrow[k] = pw1[tid*24 + k];
    float bias = pb1[tid];
    #pragma unroll 2
    for (int i = 0; i < 64; ++i) {
      float s = bias;
      #pragma unroll
      for (int k = 0; k < 24; k += 4) {
        float4 a4 = *(const float4*)(&attrS[i][k]);
        s += a4.x*wrow[k] + a4.y*wrow[k+1] + a4.z*wrow[k+2] + a4.w*wrow[k+3];
      }
      s = fmaxf(s, 0.f);
      *(ushort_t*)(m1s + i*512 + ((tid*2) ^ ((i&15)<<4))) = f2b(s);
    }
  }
  __syncthreads();

  // ---- GEMM2: p2 = relu(p1 @ pW2.T + pb2); weighted col-sum -> pagg -------
  {
    f32x4 acc[4][4];
    #pragma unroll
    for (int rt = 0; rt < 4; ++rt)
      #pragma unroll
      for (int nt = 0; nt < 4; ++nt) acc[rt][nt] = zero;
    for (int kk = 0; kk < 8; ++kk) {
      bf16x8 afr[4];
      #pragma unroll
      for (int rt = 0; rt < 4; ++rt) {
        int row = rt*16 + lrow;
        afr[rt] = *reinterpret_cast<const bf16x8*>(
            m1s + row*512 + ((kk*64 + lk*16) ^ ((row&15)<<4)));
      }
      #pragma unroll
      for (int nt = 0; nt < 4; ++nt) {
        int col = wv*64 + nt*16 + lrow;
        bf16x8 bfr = *reinterpret_cast<const bf16x8*>(pw2b + col*HH + kk*32 + lk*8);
        #pragma unroll
        for (int rt = 0; rt < 4; ++rt)
          acc[rt][nt] = __builtin_amdgcn_mfma_f32_16x16x32_bf16(afr[rt], bfr, acc[rt][nt], 0, 0, 0);
      }
    }
    float* paggOut = half ? pagg1 : pagg0;
    #pragma unroll
    for (int nt = 0; nt < 4; ++nt) {
      int col = wv*64 + nt*16 + lrow;
      float bias = pb2[col];
      float p = 0.f;
      #pragma unroll
      for (int rt = 0; rt < 4; ++rt)
        #pragma unroll
        for (int r = 0; r < 4; ++r) {
          int row = rt*16 + lk*4 + r;
          p += fmaxf(acc[rt][nt][r] + bias, 0.f) * wgtS[row];
        }
      p += __shfl_xor(p, 16);
      p += __shfl_xor(p, 32);
      if (lane < 16)
        paggOut[(b*NN + j)*HH + wv*64 + nt*16 + lane] = p * (1.0f/127.0f);
    }
  }
}

// ---------------------------------------------------------------------------
// K4: GRU gates + output MLP + global-frame outputs.
// ---------------------------------------------------------------------------
__global__ __launch_bounds__(256) void k_gru(
    const float* __restrict__ inputs, const float* __restrict__ hidden,
    const float* __restrict__ geom, const float* __restrict__ relf,
    const float* __restrict__ agg0, const float* __restrict__ agg1,
    const float* __restrict__ pagg0, const float* __restrict__ pagg1,
    const float* __restrict__ hr_w, const float* __restrict__ hi_w, const float* __restrict__ hh_w,
    const float* __restrict__ pr_w, const float* __restrict__ pr_b,
    const float* __restrict__ pi_w, const float* __restrict__ pi_b,
    const float* __restrict__ pn_w, const float* __restrict__ pn_b,
    const float* __restrict__ ir_w, const float* __restrict__ ir_b,
    const float* __restrict__ ii_w, const float* __restrict__ ii_b,
    const float* __restrict__ in_w, const float* __restrict__ in_b,
    const float* __restrict__ ow1, const float* __restrict__ ob1,
    const float* __restrict__ ow2, const float* __restrict__ ob2,
    const float* __restrict__ ow3, const float* __restrict__ ob3,
    float* __restrict__ out_o, float* __restrict__ out_h) {
  int n = blockIdx.x >> 1, half = blockIdx.x & 1;
  int tid = threadIdx.x;
  __shared__ float paS[8][HH], agS[8][HH], hS[8][HH], t0S[8][HH], t1S[8][HH];
  __shared__ float relS[8][16];
  __shared__ float predS[8][4];

  for (int q = 0; q < 8; ++q) {
    int b = half*8 + q;
    int base = (b*NN + n)*HH;
    paS[q][tid] = pagg0[base + tid] + pagg1[base + tid];
    agS[q][tid] = agg0[base + tid] + agg1[base + tid];
    hS[q][tid]  = hidden[base + tid];
  }
  if (tid < 128) {
    int q = tid >> 4, k = tid & 15;
    int b = half*8 + q;
    relS[q][k] = (k < 15) ? relf[(b*NN + n)*16 + k] : 0.f;
  }
  __syncthreads();

  int h = tid;
  float aR[8], aI[8], aN[8], aH[8];
  float br = ir_b[h] + pr_b[h];
  float bi = ii_b[h] + pi_b[h];
  float bn = in_b[h] + pn_b[h];
  #pragma unroll
  for (int q = 0; q < 8; ++q) { aR[q]=br; aI[q]=bi; aN[q]=bn; aH[q]=0.f; }

  for (int k = 0; k < 15; ++k) {
    float wr = ir_w[h*15+k], wi = ii_w[h*15+k], wn = in_w[h*15+k];
    #pragma unroll
    for (int q = 0; q < 8; ++q) {
      float x = relS[q][k];
      aR[q] += x*wr; aI[q] += x*wi; aN[q] += x*wn;
    }
  }
  for (int k = 0; k < HH; k += 4) {
    float4 wpr = *(const float4*)(pr_w + h*HH + k);
    float4 wpi = *(const float4*)(pi_w + h*HH + k);
    float4 wpn = *(const float4*)(pn_w + h*HH + k);
    float4 whr = *(const float4*)(hr_w + h*HH + k);
    float4 whi = *(const float4*)(hi_w + h*HH + k);
    float4 whh = *(const float4*)(hh_w + h*HH + k);
    #pragma unroll
    for (int q = 0; q < 8; ++q) {
      float4 xp = *(const float4*)(&paS[q][k]);
      float4 xa = *(const float4*)(&agS[q][k]);
      aR[q] += xp.x*wpr.x + xp.y*wpr.y + xp.z*wpr.z + xp.w*wpr.w
             + xa.x*whr.x + xa.y*whr.y + xa.z*whr.z + xa.w*whr.w;
      aI[q] += xp.x*wpi.x + xp.y*wpi.y + xp.z*wpi.z + xp.w*wpi.w
             + xa.x*whi.x + xa.y*whi.y + xa.z*whi.z + xa.w*whi.w;
      aN[q] += xp.x*wpn.x + xp.y*wpn.y + xp.z*wpn.z + xp.w*wpn.w;
      aH[q] += xa.x*whh.x + xa.y*whh.y + xa.z*whh.z + xa.w*whh.w;
    }
  }
  #pragma unroll
  for (int q = 0; q < 8; ++q) {
    int b = half*8 + q;
    float r  = fast_sigmoid(aR[q]);
    float ig = fast_sigmoid(aI[q]);
    float ng = fast_tanh(aN[q] + r*aH[q]);
    float hn = (1.f - ig)*ng + ig*hS[q][h];
    out_h[(b*NN + n)*HH + h] = hn;
    t0S[q][h] = hn;
  }
  __syncthreads();

  {
    float a1[8];
    float bias = ob1[h];
    #pragma unroll
    for (int q = 0; q < 8; ++q) a1[q] = bias;
    for (int k = 0; k < HH; k += 4) {
      float4 w = *(const float4*)(ow1 + h*HH + k);
      #pragma unroll
      for (int q = 0; q < 8; ++q) {
        float4 x = *(const float4*)(&t0S[q][k]);
        a1[q] += x.x*w.x + x.y*w.y + x.z*w.z + x.w*w.w;
      }
    }
    __syncthreads();
    #pragma unroll
    for (int q = 0; q < 8; ++q) t1S[q][h] = fmaxf(a1[q], 0.f);
  }
  __syncthreads();

  {
    float a2[8];
    float bias = ob2[h];
    #pragma unroll
    for (int q = 0; q < 8; ++q) a2[q] = bias;
    for (int k = 0; k < HH; k += 4) {
      float4 w = *(const float4*)(ow2 + h*HH + k);
      #pragma unroll
      for (int q = 0; q < 8; ++q) {
        float4 x = *(const float4*)(&t1S[q][k]);
        a2[q] += x.x*w.x + x.y*w.y + x.z*w.z + x.w*w.w;
      }
    }
    __syncthreads();
    #pragma unroll
    for (int q = 0; q < 8; ++q) t0S[q][h] = fmaxf(a2[q], 0.f);
  }
  __syncthreads();

  if (tid < 32) {
    int o = tid >> 3, q = tid & 7;
    float acc = ob3[o];
    for (int k = 0; k < HH; ++k) acc += t0S[q][k]*ow3[o*HH + k];
    predS[q][o] = acc;
  }
  __syncthreads();
  if (tid < 8) {
    int q = tid;
    int b = half*8 + q;
    const float* g = geom + (b*NN + n)*16;
    float c = g[5], s = g[6];
    float p0 = predS[q][0], p1 = predS[q][1], p2 = predS[q][2], p3 = predS[q][3];
    int base = (b*NN + n)*4;
    out_o[base+0] = inputs[base+0] + (c*p0 - s*p1);
    out_o[base+1] = inputs[base+1] + (s*p0 + c*p1);
    out_o[base+2] = inputs[base+2] + (c*p2 - s*p3);
    out_o[base+3] = inputs[base+3] + (s*p2 + c*p3);
  }
}

// ---------------------------------------------------------------------------
extern "C" void kernel_launch(void* const* d_in, const int* in_sizes, int n_in,
                              void* d_out, int out_size, void* d_ws, size_t ws_size,
                              hipStream_t stream) {
  const float* inputs    = (const float*)d_in[0];
  const float* hidden    = (const float*)d_in[1];
  const float* edges     = (const float*)d_in[2];
  const float* pfield    = (const float*)d_in[3];
  const float* msg_fc1_w = (const float*)d_in[4];
  const float* msg_fc1_b = (const float*)d_in[5];
  const float* msg_fc2_w = (const float*)d_in[6];
  const float* msg_fc2_b = (const float*)d_in[7];
  const float* pm_fc1_w  = (const float*)d_in[8];
  const float* pm_fc1_b  = (const float*)d_in[9];
  const float* pm_fc2_w  = (const float*)d_in[10];
  const float* pm_fc2_b  = (const float*)d_in[11];
  const float* hr_w = (const float*)d_in[12];
  const float* hi_w = (const float*)d_in[13];
  const float* hh_w = (const float*)d_in[14];
  const float* pr_w = (const float*)d_in[15];
  const float* pr_b = (const float*)d_in[16];
  const float* pi_w = (const float*)d_in[17];
  const float* pi_b = (const float*)d_in[18];
  const float* pn_w = (const float*)d_in[19];
  const float* pn_b = (const float*)d_in[20];
  const float* ir_w = (const float*)d_in[21];
  const float* ir_b = (const float*)d_in[22];
  const float* ii_w = (const float*)d_in[23];
  const float* ii_b = (const float*)d_in[24];
  const float* in_w = (const float*)d_in[25];
  const float* in_b = (const float*)d_in[26];
  const float* ow1  = (const float*)d_in[27];
  const float* ob1  = (const float*)d_in[28];
  const float* ow2  = (const float*)d_in[29];
  const float* ob2  = (const float*)d_in[30];
  const float* ow3  = (const float*)d_in[31];
  const float* ob3  = (const float*)d_in[32];

  float* ws   = (float*)d_ws;
  float* geom = ws;                 // 32768
  float* relf = geom + 32768;       // 32768
  float* Ha   = relf + 32768;       // 524288
  float* Hb   = Ha   + 524288;      // 524288
  float* agg0 = Hb   + 524288;      // 524288
  float* agg1 = agg0 + 524288;      // 524288
  float* pagg0= agg1 + 524288;      // 524288
  float* pagg1= pagg0+ 524288;      // 524288
  ushort_t* w2b  = (ushort_t*)(pagg1 + 524288);  // 65536 bf16
  ushort_t* pw2b = w2b + HH*HH;                  // 65536 bf16

  float* out_o = (float*)d_out;           // (B,N,4)
  float* out_h = out_o + BB*NN*4;         // (B,N,H)

  k_node_geom<<<dim3(8), dim3(256), 0, stream>>>(inputs, pfield, geom, relf);
  k_cvt<<<dim3(512), dim3(256), 0, stream>>>(msg_fc2_w, pm_fc2_w, w2b, pw2b);
  k_hab<<<dim3(256), dim3(256), 0, stream>>>(hidden, msg_fc1_w, msg_fc1_b, Ha, Hb);
  k_edge<<<dim3(BB*NN*2), dim3(256), 0, stream>>>(Ha, Hb, geom, edges,
      w2b, msg_fc2_b + HH, pw2b, pm_fc2_b + HH,
      pm_fc1_w + HH*24, pm_fc1_b + HH, agg0, agg1, pagg0, pagg1);
  k_gru<<<dim3(256), dim3(256), 0, stream>>>(inputs, hidden, geom, relf,
      agg0, agg1, pagg0, pagg1,
      hr_w, hi_w, hh_w, pr_w, pr_b, pi_w, pi_b, pn_w, pn_b,
      ir_w, ir_b, ii_w, ii_b, in_w, in_b,
      ow1, ob1, ow2, ob2, ow3, ob3, out_o, out_h);
}